// Round 8
// baseline (796.783 us; speedup 1.0000x reference)
//
#include <hip/hip_runtime.h>
#include <math.h>

#define NN 255
#define TC 510
#define HTLD 512

typedef unsigned int uint32;

__device__ __forceinline__ float sigm(float x){ return 1.f/(1.f+expf(-x)); }

// relaxed agent-scope atomics for barrier flags only (bypass L2, device-visible)
__device__ __forceinline__ uint32 aloadu(const uint32* p){ return __hip_atomic_load(p, __ATOMIC_RELAXED, __HIP_MEMORY_SCOPE_AGENT); }
__device__ __forceinline__ void astoreu(uint32* p, uint32 v){ __hip_atomic_store(p, v, __ATOMIC_RELAXED, __HIP_MEMORY_SCOPE_AGENT); }

__device__ __forceinline__ void leaf_gate(const float* __restrict__ xgp, int m, float& c, float& h){
  float x0 = xgp[m], x1 = xgp[300+m], x3 = xgp[900+m];
  float u = tanhf(x0), ig = sigm(x1);
  c = ig * u;
  h = sigm(x3) * tanhf(c);
}

// Grid barrier with cache coherence: release fence (waitcnt + L2 writeback) before
// arrival, relaxed flag/gate protocol (contention-free), ONE acquire fence
// (L1/L2 invalidate) after the gate opens. Weights live in registers -> immune.
template<int NB>
__device__ __forceinline__ void gsyncf(uint32* flags, uint32 phase){
  __builtin_amdgcn_fence(__ATOMIC_RELEASE, "agent");   // drain + buffer_wbl2: publish H/C/HT
  __syncthreads();
  uint32* gate = flags + NB;
  if (blockIdx.x == 0){
    if (threadIdx.x < 64){
      for(;;){
        uint32 mn = phase;
        for (int i = 1 + (int)threadIdx.x; i < NB; i += 64)
          mn = min(mn, aloadu(&flags[i]));
        if (__all(mn >= phase)) break;
        __builtin_amdgcn_s_sleep(2);
      }
      if (threadIdx.x == 0) astoreu(gate, phase);
    }
  } else {
    if (threadIdx.x == 0){
      astoreu(&flags[blockIdx.x], phase);
      while (aloadu(gate) < phase) __builtin_amdgcn_s_sleep(2);
    }
  }
  __syncthreads();
  __builtin_amdgcn_fence(__ATOMIC_ACQUIRE, "agent");   // buffer_inv: drop stale L1/L2 lines
}

// ---------------- setup: per-level node lists as int4{gi, gl, gr, 0} ----------------
__global__ __launch_bounds__(512) void k_setup(const int* __restrict__ l1, const int* __restrict__ r1,
                                               const int* __restrict__ l2, const int* __restrict__ r2,
                                               int4* __restrict__ lists2, int* __restrict__ cnt)
{
  __shared__ int lv[TC];
  __shared__ int cs[16];
  int t = threadIdx.x;
  if (t < TC) lv[t] = 0;
  if (t < 16) cs[t] = 0;
  __syncthreads();
  for (int it = 0; it < 12; ++it){
    int nv = 0;
    if (t < TC){
      int tr = t >= NN, i = t - tr * NN;
      const int* L = tr ? l2 : l1;
      const int* R = tr ? r2 : r1;
      int l = L[i], r = R[i];
      nv = (l < 0) ? 0 : 1 + max(lv[tr * NN + l], lv[tr * NN + r]);
    }
    __syncthreads();
    if (t < TC) lv[t] = nv;
    __syncthreads();
  }
  if (t < TC){
    int tr = t >= NN, i = t - tr * NN;
    int v = min(lv[t], 15);
    int pos = atomicAdd(&cs[v], 1);
    int l = (tr ? l2 : l1)[i], r = (tr ? r2 : r1)[i];
    lists2[v * 256 + pos] = make_int4(tr * NN + i, tr * NN + max(l, 0), tr * NN + max(r, 0), 0);
  }
  __syncthreads();
  if (t < 16) cnt[t] = cs[t];
}

// ---------------- persistent cooperative tree-LSTM (one launch per stage) ----------------
// NB blocks (NG node-groups x 75 m-blocks) x 256 threads; team owns row m = mblk*4+team.
// Weights in registers (fence-immune); H/C/HT via PLAIN CACHED loads/stores — coherence
// provided by gsyncf's release-writeback / acquire-invalidate per level.
template<int NB, int NG>
__global__ __launch_bounds__(256, 3) void k_tree(
    const int* __restrict__ l1, const int* __restrict__ l2,
    const float* __restrict__ Wl, const float* __restrict__ Wr,
    const float* __restrict__ xg,
    float* __restrict__ H, float* __restrict__ C, float* __restrict__ HT,
    const int4* __restrict__ lists2, const int* __restrict__ cnt,
    uint32* __restrict__ bar)
{
  __shared__ float Hs[16][2][320];
  __shared__ float Cs[16][4][2];
  __shared__ float Xs[16][4][4];
  __shared__ int4 nfo[288];
  __shared__ int lvoff[9];

  const int tid = threadIdx.x;
  const int lane = tid & 63, team = tid >> 6;
  const int mblk = blockIdx.x % 75, grp = blockIdx.x / 75;
  const int m = mblk * 4 + team;

  // ---- one-time: weight slice into registers (K interleaved by lane) ----
  float wl[5][5], wr[5][5];
  #pragma unroll
  for (int g = 0; g < 5; ++g)
    #pragma unroll
    for (int j = 0; j < 5; ++j){
      int d = j * 64 + lane;
      size_t o = ((size_t)g * 300 + m) * 300 + d;
      wl[g][j] = (d < 300) ? Wl[o] : 0.f;
      wr[g][j] = (d < 300) ? Wr[o] : 0.f;
    }

  if (tid == 0){ int o = 0; for (int lv = 1; lv <= 7; ++lv){ lvoff[lv] = o; o += cnt[lv]; } }
  __syncthreads();
  for (int lv = 1; lv <= 7; ++lv)
    for (int i = tid; i < cnt[lv]; i += 256)
      nfo[lvoff[lv] + i] = lists2[lv * 256 + i];

  // ---- phase 0: all leaves' H,C (+ transposed H), plain cached stores ----
  for (int e = blockIdx.x * 256 + tid; e < TC * 300; e += 256 * NB){
    int gi = e / 300, mm = e - gi * 300;
    int tr = gi >= NN, node = gi - tr * NN;
    if ((tr ? l2 : l1)[node] < 0){
      float c, h; leaf_gate(xg + (size_t)gi * 1200, mm, c, h);
      C[(size_t)gi * 300 + mm] = c;
      H[(size_t)gi * 300 + mm] = h;
      HT[(size_t)mm * HTLD + gi] = h;
    }
  }
  gsyncf<NB>(bar, 1);

  // ---- levels 1..7 ----
  for (int lv = 1; lv <= 7; ++lv){
    int nodes = cnt[lv];
    int npg = (nodes + NG - 1) / NG;
    int n0 = grp * npg, n1 = min(nodes, n0 + npg);
    for (int nb0 = n0; nb0 < n1; nb0 += 16){
      int nch = min(16, n1 - nb0);
      int base = lvoff[lv] + nb0;
      __syncthreads();
      // -- Hs staging: per wave, 2 passes x 2 nodes, reg-staged unrolled cached loads --
      #pragma unroll
      for (int p = 0; p < 2; ++p){
        int niA = team + p * 8, niB = niA + 4;
        bool vA = niA < nch, vB = niB < nch;
        int4 na = vA ? nfo[base + niA] : make_int4(0, 0, 0, 0);
        int4 nb4 = vB ? nfo[base + niB] : make_int4(0, 0, 0, 0);
        int d0 = lane, d1 = 64 + lane, d2 = 128 + lane, d3 = 192 + lane, d4 = 256 + lane;
        bool i4 = d4 < 300;
        #define LDH(ci, dd, ok) ((ok) ? H[(size_t)(ci) * 300 + (dd)] : 0.f)
        float a0=LDH(na.y,d0,vA), a1=LDH(na.y,d1,vA), a2=LDH(na.y,d2,vA), a3=LDH(na.y,d3,vA), a4=LDH(na.y,d4,vA&&i4);
        float a5=LDH(na.z,d0,vA), a6=LDH(na.z,d1,vA), a7=LDH(na.z,d2,vA), a8=LDH(na.z,d3,vA), a9=LDH(na.z,d4,vA&&i4);
        float c0=LDH(nb4.y,d0,vB), c1=LDH(nb4.y,d1,vB), c2=LDH(nb4.y,d2,vB), c3=LDH(nb4.y,d3,vB), c4=LDH(nb4.y,d4,vB&&i4);
        float c5=LDH(nb4.z,d0,vB), c6=LDH(nb4.z,d1,vB), c7=LDH(nb4.z,d2,vB), c8=LDH(nb4.z,d3,vB), c9=LDH(nb4.z,d4,vB&&i4);
        #undef LDH
        if (vA){
          Hs[niA][0][d0]=a0; Hs[niA][0][d1]=a1; Hs[niA][0][d2]=a2; Hs[niA][0][d3]=a3; Hs[niA][0][d4]=a4;
          Hs[niA][1][d0]=a5; Hs[niA][1][d1]=a6; Hs[niA][1][d2]=a7; Hs[niA][1][d3]=a8; Hs[niA][1][d4]=a9;
        }
        if (vB){
          Hs[niB][0][d0]=c0; Hs[niB][0][d1]=c1; Hs[niB][0][d2]=c2; Hs[niB][0][d3]=c3; Hs[niB][0][d4]=c4;
          Hs[niB][1][d0]=c5; Hs[niB][1][d1]=c6; Hs[niB][1][d2]=c7; Hs[niB][1][d3]=c8; Hs[niB][1][d4]=c9;
        }
      }
      // -- Cs prefetch (children C), cached --
      if (tid < 128){
        int ni = tid >> 3, tm = (tid >> 1) & 3, side = tid & 1;
        if (ni < nch){
          int4 nn = nfo[base + ni];
          int child = side ? nn.z : nn.y;
          Cs[ni][tm][side] = C[(size_t)child * 300 + mblk * 4 + tm];
        }
      }
      // -- Xs prefetch (xg gate terms), cached --
      {
        int ni = tid >> 4, tm = (tid >> 2) & 3, g = tid & 3;
        if (ni < nch){
          int4 nn = nfo[base + ni];
          Xs[ni][tm][g] = xg[(size_t)nn.x * 1200 + g * 300 + mblk * 4 + tm];
        }
      }
      __syncthreads();
      #pragma unroll 2
      for (int ni = 0; ni < nch; ++ni){
        float p0 = 0.f, p1 = 0.f, p2 = 0.f, p3 = 0.f, p4 = 0.f;
        #pragma unroll
        for (int j = 0; j < 5; ++j){
          float hl = Hs[ni][0][j * 64 + lane];
          float hr = Hs[ni][1][j * 64 + lane];
          p0 += wl[0][j] * hl + wr[0][j] * hr;
          p1 += wl[1][j] * hl + wr[1][j] * hr;
          p2 += wl[2][j] * hl + wr[2][j] * hr;
          p3 += wl[3][j] * hl + wr[3][j] * hr;
          p4 += wl[4][j] * hl + wr[4][j] * hr;
        }
        #pragma unroll
        for (int off = 32; off; off >>= 1){
          p0 += __shfl_xor(p0, off); p1 += __shfl_xor(p1, off); p2 += __shfl_xor(p2, off);
          p3 += __shfl_xor(p3, off); p4 += __shfl_xor(p4, off);
        }
        if (lane == 0){
          int4 nn = nfo[base + ni];
          int gi = nn.x;
          float lc = Cs[ni][team][0], rc = Cs[ni][team][1];
          float u  = tanhf(Xs[ni][team][0] + p0);
          float ig = sigm (Xs[ni][team][1] + p1);
          float lf = sigm (Xs[ni][team][2] + p2);
          float rf = sigm (Xs[ni][team][2] + p3);   // fx shared for both forgets
          float o  = sigm (Xs[ni][team][3] + p4);
          float cc = ig * u + lf * lc + rf * rc;
          float hv = o * tanhf(cc);
          C[(size_t)gi * 300 + m] = cc;
          H[(size_t)gi * 300 + m] = hv;
          HT[(size_t)m * HTLD + gi] = hv;
        }
      }
    }
    if (lv < 7) gsyncf<NB>(bar, 1 + lv);
  }
}

// ---------------- xg GEMM: out[col][r] = bias[r] + sum_d W[r][d] * Z[col][d] ----------------
__global__ __launch_bounds__(256) void k_xg(const int* __restrict__ sent1, const int* __restrict__ sent2,
                                            const int* __restrict__ l1, const int* __restrict__ l2,
                                            const float* __restrict__ emb, int pad,
                                            const float* __restrict__ W, const float* __restrict__ bias,
                                            const float* __restrict__ hsrc, float* __restrict__ out)
{
  __shared__ float Z[8][300];
  int tx = threadIdx.x, ty = threadIdx.y;
  int t = ty * 64 + tx;
  int colbase = blockIdx.y * 8;
  for (int c = 0; c < 8; ++c){
    int gcol = colbase + c;
    if (gcol < TC){
      if (hsrc){
        for (int k = t; k < 300; k += 256) Z[c][k] = hsrc[(size_t)gcol * 300 + k];
      } else {
        int tr = gcol >= NN, node = gcol - tr * NN;
        int tok = ((tr ? l2 : l1)[node] < 0) ? (tr ? sent2 : sent1)[node] : pad;
        const float* e = emb + (size_t)tok * 300;
        for (int k = t; k < 300; k += 256) Z[c][k] = e[k];
      }
    } else {
      for (int k = t; k < 300; k += 256) Z[c][k] = 0.f;
    }
  }
  __syncthreads();
  int r = blockIdx.x * 64 + tx;
  if (r < 1200){
    float a0 = 0.f, a1 = 0.f;
    const float* wp = W + (size_t)r * 300;
    for (int k = 0; k < 300; k += 4){
      float4 wv = *(const float4*)(wp + k);
      float4 z0 = *(const float4*)(&Z[ty][k]);
      float4 z1 = *(const float4*)(&Z[ty + 4][k]);
      a0 += wv.x*z0.x + wv.y*z0.y + wv.z*z0.z + wv.w*z0.w;
      a1 += wv.x*z1.x + wv.y*z1.y + wv.z*z1.z + wv.w*z1.w;
    }
    float b = bias[r];
    int g0 = colbase + ty, g1 = colbase + ty + 4;
    if (g0 < TC) out[(size_t)g0 * 1200 + r] = a0 + b;
    if (g1 < TC) out[(size_t)g1 * 1200 + r] = a1 + b;
  }
}

// ---------------- attention: one block per output row; scores via transposed H ----------------
__global__ __launch_bounds__(256) void k_attn(const float* __restrict__ H, const float* __restrict__ HT,
                                              float* __restrict__ ab)
{
  __shared__ float q[300];
  __shared__ float pr[NN];
  __shared__ float red[256];
  int b = blockIdx.x, t = threadIdx.x;
  int dir = b >= NN, i = b - dir * NN;
  const float* Ss = H + (dir ? NN * 300 : 0);
  const float* So = H + (dir ? 0 : NN * 300);
  int oppb = dir ? 0 : NN;
  for (int k = t; k < 300; k += 256) q[k] = Ss[(size_t)i * 300 + k];
  __syncthreads();
  float v = -1e30f;
  if (t < NN){
    float a = 0.f;
    const float* hp = HT + oppb + t;
    #pragma unroll 4
    for (int k = 0; k < 300; ++k) a += q[k] * hp[(size_t)k * HTLD];
    pr[t] = a; v = a;
  }
  red[t] = v; __syncthreads();
  for (int s = 128; s; s >>= 1){ if (t < s) red[t] = fmaxf(red[t], red[t + s]); __syncthreads(); }
  float mx = red[0]; __syncthreads();
  float e = 0.f;
  if (t < NN){ e = expf(pr[t] - mx); pr[t] = e; }
  red[t] = e; __syncthreads();
  for (int s = 128; s; s >>= 1){ if (t < s) red[t] += red[t + s]; __syncthreads(); }
  float inv = 1.f / red[0]; __syncthreads();
  for (int m = t; m < 300; m += 256){
    float a = 0.f;
    for (int j = 0; j < NN; ++j) a += pr[j] * So[(size_t)j * 300 + m];
    ab[(size_t)b * 300 + m] = a * inv;
  }
}

// ---------------- compare h: h = relu(Wc @ [s,a,s-a,s*a] + bc). R=300, K=1200 ----------------
__global__ __launch_bounds__(256) void k_hcmp(const float* __restrict__ Henc, const float* __restrict__ ab,
                                              const float* __restrict__ Wc, const float* __restrict__ bc,
                                              float* __restrict__ hc)
{
  __shared__ float Z[8][1200];
  int tx = threadIdx.x, ty = threadIdx.y;
  int t = ty * 64 + tx;
  int colbase = blockIdx.y * 8;
  for (int c = 0; c < 8; ++c){
    int gcol = colbase + c;
    if (gcol < TC){
      const float* sp = Henc + (size_t)gcol * 300;
      const float* ap = ab + (size_t)gcol * 300;
      for (int k = t; k < 1200; k += 256){
        int sel = k >= 900 ? 3 : (k >= 600 ? 2 : (k >= 300 ? 1 : 0));
        int kk = k - sel * 300;
        float s = sp[kk], a = ap[kk];
        Z[c][k] = sel == 0 ? s : sel == 1 ? a : sel == 2 ? (s - a) : (s * a);
      }
    } else {
      for (int k = t; k < 1200; k += 256) Z[c][k] = 0.f;
    }
  }
  __syncthreads();
  int r = blockIdx.x * 64 + tx;
  if (r < 300){
    float a0 = 0.f, a1 = 0.f;
    const float* wp = Wc + (size_t)r * 1200;
    for (int k = 0; k < 1200; k += 4){
      float4 wv = *(const float4*)(wp + k);
      float4 z0 = *(const float4*)(&Z[ty][k]);
      float4 z1 = *(const float4*)(&Z[ty + 4][k]);
      a0 += wv.x*z0.x + wv.y*z0.y + wv.z*z0.z + wv.w*z0.w;
      a1 += wv.x*z1.x + wv.y*z1.y + wv.z*z1.z + wv.w*z1.w;
    }
    float b = bc[r];
    int g0 = colbase + ty, g1 = colbase + ty + 4;
    if (g0 < TC) hc[(size_t)g0 * 300 + r] = fmaxf(a0 + b, 0.f);
    if (g1 < TC) hc[(size_t)g1 * 300 + r] = fmaxf(a1 + b, 0.f);
  }
}

// ---------------- head: mean/max aggregate (from transposed Hcmp) + MLP ----------------
__global__ __launch_bounds__(512) void k_head(const float* __restrict__ HTc,
                                              const float* __restrict__ Wa1, const float* __restrict__ ba1,
                                              const float* __restrict__ Wa2, const float* __restrict__ ba2,
                                              float* __restrict__ out)
{
  __shared__ float a_s[1200];
  __shared__ float hid[300];
  int t = threadIdx.x;
  for (int idx = t; idx < 600; idx += 512){
    int tr = idx >= 300;
    int m = idx - tr * 300;
    const float* p = HTc + (size_t)m * HTLD + tr * NN;
    float s = 0.f, mx = -1e30f;
    for (int n = 0; n < NN; ++n){ float v = p[n]; s += v; mx = fmaxf(mx, v); }
    a_s[tr * 600 + m] = s / 255.0f;
    a_s[tr * 600 + 300 + m] = mx;
  }
  __syncthreads();
  for (int h = t; h < 300; h += 512){
    float acc = ba1[h];
    const float* wp = Wa1 + (size_t)h * 1200;
    for (int k = 0; k < 1200; k += 4){
      float4 wv = *(const float4*)(wp + k);
      float4 av = *(const float4*)(&a_s[k]);
      acc += wv.x*av.x + wv.y*av.y + wv.z*av.z + wv.w*av.w;
    }
    hid[h] = fmaxf(acc, 0.f);
  }
  __syncthreads();
  if (t < 192){
    int c = t >> 6, lane = t & 63;
    float a = 0.f;
    for (int k = lane; k < 300; k += 64) a += Wa2[c * 300 + k] * hid[k];
    for (int off = 32; off; off >>= 1) a += __shfl_down(a, off);
    if (lane == 0) out[c] = a + ba2[c];
  }
}

extern "C" void kernel_launch(void* const* d_in, const int* in_sizes, int n_in,
                              void* d_out, int out_size, void* d_ws, size_t ws_size,
                              hipStream_t stream)
{
  const int*   sent1 = (const int*)d_in[0];
  const int*   sent2 = (const int*)d_in[1];
  const int*   l1    = (const int*)d_in[2];
  const int*   r1    = (const int*)d_in[3];
  const int*   l2    = (const int*)d_in[4];
  const int*   r2    = (const int*)d_in[5];
  const float* emb   = (const float*)d_in[6];
  const float* Wx_i  = (const float*)d_in[7];
  const float* bx_i  = (const float*)d_in[8];
  const float* Wl_i  = (const float*)d_in[9];
  const float* Wr_i  = (const float*)d_in[10];
  const float* Wx_c  = (const float*)d_in[11];
  const float* bx_c  = (const float*)d_in[12];
  const float* Wl_c  = (const float*)d_in[13];
  const float* Wr_c  = (const float*)d_in[14];
  const float* Wcm   = (const float*)d_in[15];
  const float* bcm   = (const float*)d_in[16];
  const float* Wa1   = (const float*)d_in[17];
  const float* ba1   = (const float*)d_in[18];
  const float* Wa2   = (const float*)d_in[19];
  const float* ba2   = (const float*)d_in[20];
  int V = in_sizes[6] / 300;
  int pad = V - 1;

  char* w = (char*)d_ws;
  uint32* bar1   = (uint32*)w;                 // flags[600]+gate, stage 1
  uint32* bar2   = (uint32*)(w + 4096);        // flags[600]+gate, stage 2
  int*    cnt    = (int*)(w + 8192);           // 16 ints
  int4*   lists2 = (int4*)(w + 8256);          // 16*256 int4
  float* xg   = (float*)(w + 8256 + 65536);    // [510][1200]
  float* Henc = xg + 612000;                   // [510][300]
  float* Hcmp = Henc + 153000;                 // [510][300]
  float* C    = Hcmp + 153000;                 // [510][300] (shared across stages)
  float* ab   = C + 153000;                    // [510][300]
  float* hc   = ab + 153000;                   // [510][300]
  float* HTe  = hc + 153000;                   // [300][512] transposed Henc
  float* HTc  = HTe + 153600;                  // [300][512] transposed Hcmp
  float* outp = (float*)d_out;

  hipMemsetAsync(bar1, 0, 8192, stream);

  // occupancy-gated 600-block variant; proven 300-block fallback
  int nb6 = 0, nCU = 0;
  hipError_t eq = hipOccupancyMaxActiveBlocksPerMultiprocessor(&nb6, reinterpret_cast<const void*>(&k_tree<600, 8>), 256, 0);
  hipError_t ec = hipDeviceGetAttribute(&nCU, hipDeviceAttributeMultiprocessorCount, 0);
  bool ok600 = (eq == hipSuccess) && (ec == hipSuccess) && (nb6 * nCU >= 600);

  k_setup<<<1, 512, 0, stream>>>(l1, r1, l2, r2, lists2, cnt);
  dim3 blk(64, 4);

  // encode stage
  k_xg<<<dim3(19, 64), blk, 0, stream>>>(sent1, sent2, l1, l2, emb, pad, Wx_i, bx_i, nullptr, xg);
  {
    void* args[] = {(void*)&l1, (void*)&l2, (void*)&Wl_i, (void*)&Wr_i, (void*)&xg,
                    (void*)&Henc, (void*)&C, (void*)&HTe, (void*)&lists2, (void*)&cnt, (void*)&bar1};
    if (ok600) hipLaunchCooperativeKernel((void*)&k_tree<600, 8>, dim3(600), dim3(256), args, 0, stream);
    else       hipLaunchCooperativeKernel((void*)&k_tree<300, 4>, dim3(300), dim3(256), args, 0, stream);
  }

  // attention
  k_attn<<<TC, 256, 0, stream>>>(Henc, HTe, ab);

  // compare stage
  k_hcmp<<<dim3(5, 64), blk, 0, stream>>>(Henc, ab, Wcm, bcm, hc);
  k_xg<<<dim3(19, 64), blk, 0, stream>>>(sent1, sent2, l1, l2, emb, pad, Wx_c, bx_c, hc, xg);
  {
    void* args[] = {(void*)&l1, (void*)&l2, (void*)&Wl_c, (void*)&Wr_c, (void*)&xg,
                    (void*)&Hcmp, (void*)&C, (void*)&HTc, (void*)&lists2, (void*)&cnt, (void*)&bar2};
    if (ok600) hipLaunchCooperativeKernel((void*)&k_tree<600, 8>, dim3(600), dim3(256), args, 0, stream);
    else       hipLaunchCooperativeKernel((void*)&k_tree<300, 4>, dim3(300), dim3(256), args, 0, stream);
  }

  // head
  k_head<<<1, 512, 0, stream>>>(HTc, Wa1, ba1, Wa2, ba2, outp);
}

// Round 9
// 471.593 us; speedup vs baseline: 1.6896x; 1.6896x over previous
//
#include <hip/hip_runtime.h>
#include <math.h>

#define NN 255
#define TC 510
#define HTLD 512

typedef unsigned int uint32;

__device__ __forceinline__ float sigm(float x){ return 1.f/(1.f+expf(-x)); }

// relaxed agent-scope accessors: coherent at the device point, no cache flushes
__device__ __forceinline__ float aload(const float* p){ return __hip_atomic_load(p, __ATOMIC_RELAXED, __HIP_MEMORY_SCOPE_AGENT); }
__device__ __forceinline__ void astore(float* p, float v){ __hip_atomic_store(p, v, __ATOMIC_RELAXED, __HIP_MEMORY_SCOPE_AGENT); }
__device__ __forceinline__ uint32 aloadu(const uint32* p){ return __hip_atomic_load(p, __ATOMIC_RELAXED, __HIP_MEMORY_SCOPE_AGENT); }
__device__ __forceinline__ void astoreu(uint32* p, uint32 v){ __hip_atomic_store(p, v, __ATOMIC_RELAXED, __HIP_MEMORY_SCOPE_AGENT); }

__device__ __forceinline__ void leaf_gate(const float* __restrict__ xgp, int m, float& c, float& h){
  float x0 = xgp[m], x1 = xgp[300+m], x3 = xgp[900+m];
  float u = tanhf(x0), ig = sigm(x1);
  c = ig * u;
  h = sigm(x3) * tanhf(c);
}

// Contention-free grid barrier (round-5 proven): per-block flag store, block 0
// scans flags and opens a monotonic gate. vmcnt drain publishes prior sc1 stores.
// NO cache-maintenance instructions (fences measured 3x slower, r8).
template<int NB>
__device__ __forceinline__ void gsync(uint32* flags, uint32 phase){
  asm volatile("s_waitcnt vmcnt(0)" ::: "memory");
  __syncthreads();
  uint32* gate = flags + NB;
  if (blockIdx.x == 0){
    if (threadIdx.x < 64){
      for(;;){
        uint32 mn = phase;
        for (int i = 1 + (int)threadIdx.x; i < NB; i += 64)
          mn = min(mn, aloadu(&flags[i]));
        if (__all(mn >= phase)) break;
        __builtin_amdgcn_s_sleep(2);
      }
      if (threadIdx.x == 0) astoreu(gate, phase);
    }
  } else {
    if (threadIdx.x == 0){
      astoreu(&flags[blockIdx.x], phase);
      while (aloadu(gate) < phase) __builtin_amdgcn_s_sleep(2);
    }
  }
  __syncthreads();
}

// ---------------- setup: per-level node lists as int4{gi, gl, gr, 0} ----------------
__global__ __launch_bounds__(512) void k_setup(const int* __restrict__ l1, const int* __restrict__ r1,
                                               const int* __restrict__ l2, const int* __restrict__ r2,
                                               int4* __restrict__ lists2, int* __restrict__ cnt)
{
  __shared__ int lv[TC];
  __shared__ int cs[16];
  int t = threadIdx.x;
  if (t < TC) lv[t] = 0;
  if (t < 16) cs[t] = 0;
  __syncthreads();
  for (int it = 0; it < 12; ++it){
    int nv = 0;
    if (t < TC){
      int tr = t >= NN, i = t - tr * NN;
      const int* L = tr ? l2 : l1;
      const int* R = tr ? r2 : r1;
      int l = L[i], r = R[i];
      nv = (l < 0) ? 0 : 1 + max(lv[tr * NN + l], lv[tr * NN + r]);
    }
    __syncthreads();
    if (t < TC) lv[t] = nv;
    __syncthreads();
  }
  if (t < TC){
    int tr = t >= NN, i = t - tr * NN;
    int v = min(lv[t], 15);
    int pos = atomicAdd(&cs[v], 1);
    int l = (tr ? l2 : l1)[i], r = (tr ? r2 : r1)[i];
    lists2[v * 256 + pos] = make_int4(tr * NN + i, tr * NN + max(l, 0), tr * NN + max(r, 0), 0);
  }
  __syncthreads();
  if (t < 16) cnt[t] = cs[t];
}

// ---------------- persistent cooperative tree-LSTM (round-5 body, templated grid) ----------------
// NB = NG*75 blocks x 256 threads; team owns row m = mblk*4+team; weights in registers;
// H/C/HT via relaxed agent atomics (proven fastest coherence discipline).
template<int NB, int NG>
__global__ __launch_bounds__(256, 3) void k_tree(
    const int* __restrict__ l1, const int* __restrict__ l2,
    const float* __restrict__ Wl, const float* __restrict__ Wr,
    const float* __restrict__ xg,
    float* __restrict__ H, float* __restrict__ C, float* __restrict__ HT,
    const int4* __restrict__ lists2, const int* __restrict__ cnt,
    uint32* __restrict__ bar)
{
  __shared__ float Hs[16][2][320];
  __shared__ float Cs[16][4][2];
  __shared__ float Xs[16][4][4];
  __shared__ int4 nfo[288];
  __shared__ int lvoff[9];

  const int tid = threadIdx.x;
  const int lane = tid & 63, team = tid >> 6;
  const int mblk = blockIdx.x % 75, grp = blockIdx.x / 75;
  const int m = mblk * 4 + team;

  float wl[5][5], wr[5][5];
  #pragma unroll
  for (int g = 0; g < 5; ++g)
    #pragma unroll
    for (int j = 0; j < 5; ++j){
      int d = j * 64 + lane;
      size_t o = ((size_t)g * 300 + m) * 300 + d;
      wl[g][j] = (d < 300) ? Wl[o] : 0.f;
      wr[g][j] = (d < 300) ? Wr[o] : 0.f;
    }

  if (tid == 0){ int o = 0; for (int lv = 1; lv <= 7; ++lv){ lvoff[lv] = o; o += cnt[lv]; } }
  __syncthreads();
  for (int lv = 1; lv <= 7; ++lv)
    for (int i = tid; i < cnt[lv]; i += 256)
      nfo[lvoff[lv] + i] = lists2[lv * 256 + i];

  // ---- phase 0: all leaves' H,C (+ transposed H) ----
  for (int e = blockIdx.x * 256 + tid; e < TC * 300; e += 256 * NB){
    int gi = e / 300, mm = e - gi * 300;
    int tr = gi >= NN, node = gi - tr * NN;
    if ((tr ? l2 : l1)[node] < 0){
      float c, h; leaf_gate(xg + (size_t)gi * 1200, mm, c, h);
      astore(&C[(size_t)gi * 300 + mm], c);
      astore(&H[(size_t)gi * 300 + mm], h);
      astore(&HT[(size_t)mm * HTLD + gi], h);
    }
  }
  gsync<NB>(bar, 1);

  // ---- levels 1..7 ----
  for (int lv = 1; lv <= 7; ++lv){
    int nodes = cnt[lv];
    int npg = (nodes + NG - 1) / NG;
    int n0 = grp * npg, n1 = min(nodes, n0 + npg);
    for (int nb0 = n0; nb0 < n1; nb0 += 16){
      int nch = min(16, n1 - nb0);
      int base = lvoff[lv] + nb0;
      __syncthreads();
      // -- Hs staging: per wave, 2 passes x 2 nodes, reg-staged unrolled agent loads --
      #pragma unroll
      for (int p = 0; p < 2; ++p){
        int niA = team + p * 8, niB = niA + 4;
        bool vA = niA < nch, vB = niB < nch;
        int4 na = vA ? nfo[base + niA] : make_int4(0, 0, 0, 0);
        int4 nb4 = vB ? nfo[base + niB] : make_int4(0, 0, 0, 0);
        int d0 = lane, d1 = 64 + lane, d2 = 128 + lane, d3 = 192 + lane, d4 = 256 + lane;
        bool i4 = d4 < 300;
        #define LDH(ci, dd, ok) ((ok) ? aload(&H[(size_t)(ci) * 300 + (dd)]) : 0.f)
        float a0=LDH(na.y,d0,vA), a1=LDH(na.y,d1,vA), a2=LDH(na.y,d2,vA), a3=LDH(na.y,d3,vA), a4=LDH(na.y,d4,vA&&i4);
        float a5=LDH(na.z,d0,vA), a6=LDH(na.z,d1,vA), a7=LDH(na.z,d2,vA), a8=LDH(na.z,d3,vA), a9=LDH(na.z,d4,vA&&i4);
        float c0=LDH(nb4.y,d0,vB), c1=LDH(nb4.y,d1,vB), c2=LDH(nb4.y,d2,vB), c3=LDH(nb4.y,d3,vB), c4=LDH(nb4.y,d4,vB&&i4);
        float c5=LDH(nb4.z,d0,vB), c6=LDH(nb4.z,d1,vB), c7=LDH(nb4.z,d2,vB), c8=LDH(nb4.z,d3,vB), c9=LDH(nb4.z,d4,vB&&i4);
        #undef LDH
        if (vA){
          Hs[niA][0][d0]=a0; Hs[niA][0][d1]=a1; Hs[niA][0][d2]=a2; Hs[niA][0][d3]=a3; Hs[niA][0][d4]=a4;
          Hs[niA][1][d0]=a5; Hs[niA][1][d1]=a6; Hs[niA][1][d2]=a7; Hs[niA][1][d3]=a8; Hs[niA][1][d4]=a9;
        }
        if (vB){
          Hs[niB][0][d0]=c0; Hs[niB][0][d1]=c1; Hs[niB][0][d2]=c2; Hs[niB][0][d3]=c3; Hs[niB][0][d4]=c4;
          Hs[niB][1][d0]=c5; Hs[niB][1][d1]=c6; Hs[niB][1][d2]=c7; Hs[niB][1][d3]=c8; Hs[niB][1][d4]=c9;
        }
      }
      if (tid < 128){
        int ni = tid >> 3, tm = (tid >> 1) & 3, side = tid & 1;
        if (ni < nch){
          int4 nn = nfo[base + ni];
          int child = side ? nn.z : nn.y;
          Cs[ni][tm][side] = aload(&C[(size_t)child * 300 + mblk * 4 + tm]);
        }
      }
      {
        int ni = tid >> 4, tm = (tid >> 2) & 3, g = tid & 3;
        if (ni < nch){
          int4 nn = nfo[base + ni];
          Xs[ni][tm][g] = xg[(size_t)nn.x * 1200 + g * 300 + mblk * 4 + tm];
        }
      }
      __syncthreads();
      #pragma unroll 2
      for (int ni = 0; ni < nch; ++ni){
        float p0 = 0.f, p1 = 0.f, p2 = 0.f, p3 = 0.f, p4 = 0.f;
        #pragma unroll
        for (int j = 0; j < 5; ++j){
          float hl = Hs[ni][0][j * 64 + lane];
          float hr = Hs[ni][1][j * 64 + lane];
          p0 += wl[0][j] * hl + wr[0][j] * hr;
          p1 += wl[1][j] * hl + wr[1][j] * hr;
          p2 += wl[2][j] * hl + wr[2][j] * hr;
          p3 += wl[3][j] * hl + wr[3][j] * hr;
          p4 += wl[4][j] * hl + wr[4][j] * hr;
        }
        #pragma unroll
        for (int off = 32; off; off >>= 1){
          p0 += __shfl_xor(p0, off); p1 += __shfl_xor(p1, off); p2 += __shfl_xor(p2, off);
          p3 += __shfl_xor(p3, off); p4 += __shfl_xor(p4, off);
        }
        if (lane == 0){
          int4 nn = nfo[base + ni];
          int gi = nn.x;
          float lc = Cs[ni][team][0], rc = Cs[ni][team][1];
          float u  = tanhf(Xs[ni][team][0] + p0);
          float ig = sigm (Xs[ni][team][1] + p1);
          float lf = sigm (Xs[ni][team][2] + p2);
          float rf = sigm (Xs[ni][team][2] + p3);   // fx shared for both forgets
          float o  = sigm (Xs[ni][team][3] + p4);
          float cc = ig * u + lf * lc + rf * rc;
          float hv = o * tanhf(cc);
          astore(&C[(size_t)gi * 300 + m], cc);
          astore(&H[(size_t)gi * 300 + m], hv);
          astore(&HT[(size_t)m * HTLD + gi], hv);
        }
      }
    }
    if (lv < 7) gsync<NB>(bar, 1 + lv);
  }
}

// ---------------- xg GEMM: out[col][r] = bias[r] + sum_d W[r][d] * Z[col][d] ----------------
__global__ __launch_bounds__(256) void k_xg(const int* __restrict__ sent1, const int* __restrict__ sent2,
                                            const int* __restrict__ l1, const int* __restrict__ l2,
                                            const float* __restrict__ emb, int pad,
                                            const float* __restrict__ W, const float* __restrict__ bias,
                                            const float* __restrict__ hsrc, float* __restrict__ out)
{
  __shared__ float Z[8][300];
  int tx = threadIdx.x, ty = threadIdx.y;
  int t = ty * 64 + tx;
  int colbase = blockIdx.y * 8;
  for (int c = 0; c < 8; ++c){
    int gcol = colbase + c;
    if (gcol < TC){
      if (hsrc){
        for (int k = t; k < 300; k += 256) Z[c][k] = hsrc[(size_t)gcol * 300 + k];
      } else {
        int tr = gcol >= NN, node = gcol - tr * NN;
        int tok = ((tr ? l2 : l1)[node] < 0) ? (tr ? sent2 : sent1)[node] : pad;
        const float* e = emb + (size_t)tok * 300;
        for (int k = t; k < 300; k += 256) Z[c][k] = e[k];
      }
    } else {
      for (int k = t; k < 300; k += 256) Z[c][k] = 0.f;
    }
  }
  __syncthreads();
  int r = blockIdx.x * 64 + tx;
  if (r < 1200){
    float a0 = 0.f, a1 = 0.f;
    const float* wp = W + (size_t)r * 300;
    for (int k = 0; k < 300; k += 4){
      float4 wv = *(const float4*)(wp + k);
      float4 z0 = *(const float4*)(&Z[ty][k]);
      float4 z1 = *(const float4*)(&Z[ty + 4][k]);
      a0 += wv.x*z0.x + wv.y*z0.y + wv.z*z0.z + wv.w*z0.w;
      a1 += wv.x*z1.x + wv.y*z1.y + wv.z*z1.z + wv.w*z1.w;
    }
    float b = bias[r];
    int g0 = colbase + ty, g1 = colbase + ty + 4;
    if (g0 < TC) out[(size_t)g0 * 1200 + r] = a0 + b;
    if (g1 < TC) out[(size_t)g1 * 1200 + r] = a1 + b;
  }
}

// ---------------- attention v2: 4 rows/block, dir-aligned (128 blocks) ----------------
__global__ __launch_bounds__(256) void k_attn2(const float* __restrict__ H, const float* __restrict__ HT,
                                               float* __restrict__ ab)
{
  __shared__ float q[4][304];
  __shared__ float S[4][256];
  __shared__ float red[256];
  __shared__ float invs[4];
  int t = threadIdx.x;
  int dir = blockIdx.x >= 64;
  int r0 = (blockIdx.x - dir * 64) * 4;
  int nr = min(4, NN - r0);
  const float* Ss = H + (dir ? (size_t)NN * 300 : 0);
  const float* So = H + (dir ? 0 : (size_t)NN * 300);
  int oppb = dir ? 0 : NN;

  for (int idx = t; idx < 4 * 304; idx += 256){
    int r = idx / 304, k = idx - r * 304;
    q[r][k] = (r < nr && k < 300) ? Ss[(size_t)(r0 + r) * 300 + k] : 0.f;
  }
  __syncthreads();

  // QK^T: thread t = opposite node j; 4 accumulators share each HT load
  float s0 = 0.f, s1 = 0.f, s2 = 0.f, s3 = 0.f;
  if (t < NN){
    const float* hp = HT + oppb + t;
    #pragma unroll 4
    for (int k = 0; k < 300; ++k){
      float ht = hp[(size_t)k * HTLD];
      s0 += q[0][k] * ht; s1 += q[1][k] * ht; s2 += q[2][k] * ht; s3 += q[3][k] * ht;
    }
  }
  S[0][t] = (t < NN) ? s0 : -1e30f;
  S[1][t] = (t < NN) ? s1 : -1e30f;
  S[2][t] = (t < NN) ? s2 : -1e30f;
  S[3][t] = (t < NN) ? s3 : -1e30f;
  __syncthreads();

  // softmax per row
  for (int r = 0; r < nr; ++r){
    red[t] = S[r][t];
    __syncthreads();
    for (int s = 128; s; s >>= 1){ if (t < s) red[t] = fmaxf(red[t], red[t + s]); __syncthreads(); }
    float mx = red[0];
    __syncthreads();
    float e = (t < NN) ? expf(S[r][t] - mx) : 0.f;
    S[r][t] = e;
    red[t] = e;
    __syncthreads();
    for (int s = 128; s; s >>= 1){ if (t < s) red[t] += red[t + s]; __syncthreads(); }
    if (t == 0) invs[r] = 1.f / red[0];
    __syncthreads();
  }

  // PV: thread owns m = t (and m2 = t+256 when <300); pr broadcast from LDS
  float a0=0,a1=0,a2=0,a3=0, b0=0,b1=0,b2=0,b3=0;
  int m2 = t + 256;
  bool has2 = m2 < 300;
  for (int j = 0; j < NN; ++j){
    const float* sp = So + (size_t)j * 300;
    float v1 = (t < 300) ? sp[t] : 0.f;
    float v2 = has2 ? sp[m2] : 0.f;
    float p0 = S[0][j], p1 = S[1][j], p2 = S[2][j], p3 = S[3][j];
    a0 += p0 * v1; a1 += p1 * v1; a2 += p2 * v1; a3 += p3 * v1;
    b0 += p0 * v2; b1 += p1 * v2; b2 += p2 * v2; b3 += p3 * v2;
  }
  float accs1[4] = {a0, a1, a2, a3};
  float accs2[4] = {b0, b1, b2, b3};
  for (int r = 0; r < nr; ++r){
    size_t rowo = (size_t)(dir * NN + r0 + r) * 300;
    if (t < 300) ab[rowo + t] = accs1[r] * invs[r];
    if (has2)    ab[rowo + m2] = accs2[r] * invs[r];
  }
}

// ---------------- compare h: h = relu(Wc @ [s,a,s-a,s*a] + bc). R=300, K=1200 ----------------
__global__ __launch_bounds__(256) void k_hcmp(const float* __restrict__ Henc, const float* __restrict__ ab,
                                              const float* __restrict__ Wc, const float* __restrict__ bc,
                                              float* __restrict__ hc)
{
  __shared__ float Z[8][1200];
  int tx = threadIdx.x, ty = threadIdx.y;
  int t = ty * 64 + tx;
  int colbase = blockIdx.y * 8;
  for (int c = 0; c < 8; ++c){
    int gcol = colbase + c;
    if (gcol < TC){
      const float* sp = Henc + (size_t)gcol * 300;
      const float* ap = ab + (size_t)gcol * 300;
      for (int k = t; k < 1200; k += 256){
        int sel = k >= 900 ? 3 : (k >= 600 ? 2 : (k >= 300 ? 1 : 0));
        int kk = k - sel * 300;
        float s = sp[kk], a = ap[kk];
        Z[c][k] = sel == 0 ? s : sel == 1 ? a : sel == 2 ? (s - a) : (s * a);
      }
    } else {
      for (int k = t; k < 1200; k += 256) Z[c][k] = 0.f;
    }
  }
  __syncthreads();
  int r = blockIdx.x * 64 + tx;
  if (r < 300){
    float a0 = 0.f, a1 = 0.f;
    const float* wp = Wc + (size_t)r * 1200;
    for (int k = 0; k < 1200; k += 4){
      float4 wv = *(const float4*)(wp + k);
      float4 z0 = *(const float4*)(&Z[ty][k]);
      float4 z1 = *(const float4*)(&Z[ty + 4][k]);
      a0 += wv.x*z0.x + wv.y*z0.y + wv.z*z0.z + wv.w*z0.w;
      a1 += wv.x*z1.x + wv.y*z1.y + wv.z*z1.z + wv.w*z1.w;
    }
    float b = bc[r];
    int g0 = colbase + ty, g1 = colbase + ty + 4;
    if (g0 < TC) hc[(size_t)g0 * 300 + r] = fmaxf(a0 + b, 0.f);
    if (g1 < TC) hc[(size_t)g1 * 300 + r] = fmaxf(a1 + b, 0.f);
  }
}

// ---------------- head, parallelized: agg (600 blocks) -> mlp1 (300) -> mlp2 (1) ----------------
__global__ __launch_bounds__(256) void k_agg(const float* __restrict__ HTc, float* __restrict__ agg)
{
  __shared__ float red[256];
  int idx = blockIdx.x;                 // 0..599: tr*300 + m
  int tr = idx / 300, m = idx - tr * 300;
  int t = threadIdx.x;
  const float* p = HTc + (size_t)m * HTLD + tr * NN;
  float v = (t < NN) ? p[t] : 0.f;
  red[t] = v;
  __syncthreads();
  for (int s = 128; s; s >>= 1){ if (t < s) red[t] += red[t + s]; __syncthreads(); }
  float sum = red[0];
  __syncthreads();
  red[t] = (t < NN) ? v : -1e30f;
  __syncthreads();
  for (int s = 128; s; s >>= 1){ if (t < s) red[t] = fmaxf(red[t], red[t + s]); __syncthreads(); }
  if (t == 0){
    agg[tr * 600 + m] = sum / 255.f;
    agg[tr * 600 + 300 + m] = red[0];
  }
}

__global__ __launch_bounds__(256) void k_mlp1(const float* __restrict__ agg,
                                              const float* __restrict__ Wa1, const float* __restrict__ ba1,
                                              float* __restrict__ hid)
{
  __shared__ float red[256];
  int h = blockIdx.x, t = threadIdx.x;
  const float* wp = Wa1 + (size_t)h * 1200;
  float a = 0.f;
  for (int k = t; k < 1200; k += 256) a += wp[k] * agg[k];
  red[t] = a;
  __syncthreads();
  for (int s = 128; s; s >>= 1){ if (t < s) red[t] += red[t + s]; __syncthreads(); }
  if (t == 0) hid[h] = fmaxf(red[0] + ba1[h], 0.f);
}

__global__ __launch_bounds__(256) void k_mlp2(const float* __restrict__ hid,
                                              const float* __restrict__ Wa2, const float* __restrict__ ba2,
                                              float* __restrict__ out)
{
  __shared__ float h_s[300];
  int t = threadIdx.x;
  for (int k = t; k < 300; k += 256) h_s[k] = hid[k];
  __syncthreads();
  if (t < 192){
    int c = t >> 6, ln = t & 63;
    float a = 0.f;
    for (int k = ln; k < 300; k += 64) a += Wa2[c * 300 + k] * h_s[k];
    #pragma unroll
    for (int off = 32; off; off >>= 1) a += __shfl_down(a, off);
    if (ln == 0) out[c] = a + ba2[c];
  }
}

extern "C" void kernel_launch(void* const* d_in, const int* in_sizes, int n_in,
                              void* d_out, int out_size, void* d_ws, size_t ws_size,
                              hipStream_t stream)
{
  const int*   sent1 = (const int*)d_in[0];
  const int*   sent2 = (const int*)d_in[1];
  const int*   l1    = (const int*)d_in[2];
  const int*   r1    = (const int*)d_in[3];
  const int*   l2    = (const int*)d_in[4];
  const int*   r2    = (const int*)d_in[5];
  const float* emb   = (const float*)d_in[6];
  const float* Wx_i  = (const float*)d_in[7];
  const float* bx_i  = (const float*)d_in[8];
  const float* Wl_i  = (const float*)d_in[9];
  const float* Wr_i  = (const float*)d_in[10];
  const float* Wx_c  = (const float*)d_in[11];
  const float* bx_c  = (const float*)d_in[12];
  const float* Wl_c  = (const float*)d_in[13];
  const float* Wr_c  = (const float*)d_in[14];
  const float* Wcm   = (const float*)d_in[15];
  const float* bcm   = (const float*)d_in[16];
  const float* Wa1   = (const float*)d_in[17];
  const float* ba1   = (const float*)d_in[18];
  const float* Wa2   = (const float*)d_in[19];
  const float* ba2   = (const float*)d_in[20];
  int V = in_sizes[6] / 300;
  int pad = V - 1;

  char* w = (char*)d_ws;
  uint32* bar1   = (uint32*)w;                 // flags[600]+gate, stage 1
  uint32* bar2   = (uint32*)(w + 4096);        // flags[600]+gate, stage 2
  int*    cnt    = (int*)(w + 8192);           // 16 ints
  int4*   lists2 = (int4*)(w + 8256);          // 16*256 int4
  float* xg   = (float*)(w + 8256 + 65536);    // [510][1200]
  float* Henc = xg + 612000;                   // [510][300]
  float* Hcmp = Henc + 153000;                 // [510][300]
  float* C    = Hcmp + 153000;                 // [510][300] (shared across stages)
  float* ab   = C + 153000;                    // [510][300]
  float* hc   = ab + 153000;                   // [510][300]
  float* HTe  = hc + 153000;                   // [300][512] transposed Henc
  float* HTc  = HTe + 153600;                  // [300][512] transposed Hcmp
  float* agg  = HTc + 153600;                  // [1200]
  float* hid  = agg + 1200;                    // [304]
  float* outp = (float*)d_out;

  hipMemsetAsync(bar1, 0, 8192, stream);

  // occupancy-gated 600-block tree; proven 300-block fallback
  int nb6 = 0, nCU = 0;
  hipError_t eq = hipOccupancyMaxActiveBlocksPerMultiprocessor(&nb6, reinterpret_cast<const void*>(&k_tree<600, 8>), 256, 0);
  hipError_t ec = hipDeviceGetAttribute(&nCU, hipDeviceAttributeMultiprocessorCount, 0);
  bool ok600 = (eq == hipSuccess) && (ec == hipSuccess) && (nb6 * nCU >= 600);

  k_setup<<<1, 512, 0, stream>>>(l1, r1, l2, r2, lists2, cnt);
  dim3 blk(64, 4);

  // encode stage
  k_xg<<<dim3(19, 64), blk, 0, stream>>>(sent1, sent2, l1, l2, emb, pad, Wx_i, bx_i, nullptr, xg);
  {
    void* args[] = {(void*)&l1, (void*)&l2, (void*)&Wl_i, (void*)&Wr_i, (void*)&xg,
                    (void*)&Henc, (void*)&C, (void*)&HTe, (void*)&lists2, (void*)&cnt, (void*)&bar1};
    if (ok600) hipLaunchCooperativeKernel((void*)&k_tree<600, 8>, dim3(600), dim3(256), args, 0, stream);
    else       hipLaunchCooperativeKernel((void*)&k_tree<300, 4>, dim3(300), dim3(256), args, 0, stream);
  }

  // attention (4 rows/block, dir-aligned)
  k_attn2<<<128, 256, 0, stream>>>(Henc, HTe, ab);

  // compare stage
  k_hcmp<<<dim3(5, 64), blk, 0, stream>>>(Henc, ab, Wcm, bcm, hc);
  k_xg<<<dim3(19, 64), blk, 0, stream>>>(sent1, sent2, l1, l2, emb, pad, Wx_c, bx_c, hc, xg);
  {
    void* args[] = {(void*)&l1, (void*)&l2, (void*)&Wl_c, (void*)&Wr_c, (void*)&xg,
                    (void*)&Hcmp, (void*)&C, (void*)&HTc, (void*)&lists2, (void*)&cnt, (void*)&bar2};
    if (ok600) hipLaunchCooperativeKernel((void*)&k_tree<600, 8>, dim3(600), dim3(256), args, 0, stream);
    else       hipLaunchCooperativeKernel((void*)&k_tree<300, 4>, dim3(300), dim3(256), args, 0, stream);
  }

  // head
  k_agg<<<600, 256, 0, stream>>>(HTc, agg);
  k_mlp1<<<300, 256, 0, stream>>>(agg, Wa1, ba1, hid);
  k_mlp2<<<1, 256, 0, stream>>>(hid, Wa2, ba2, outp);
}